// Round 2
// baseline (11417.950 us; speedup 1.0000x reference)
//
#include <hip/hip_runtime.h>

typedef unsigned int uint;
typedef unsigned short u16;
typedef short s16x8 __attribute__((ext_vector_type(8)));
typedef float f32x4 __attribute__((ext_vector_type(4)));

#define MFMA16(a, b, c) __builtin_amdgcn_mfma_f32_16x16x32_bf16((a), (b), (c), 0, 0, 0)

// ---- problem constants ----
// B=64, S=512, D=512, H=512, L=2
// ws layout (bytes)
static const size_t OFF_BAR = 0;                       // 2 ints
static const size_t OFF_HB  = 256;                     // [2 layers][2 bufs][64][512] bf16 = 262144
static const size_t OFF_RHB = 262400;                  // [64][512] bf16 = 65536
static const size_t OFF_WT  = 327936;                  // [2][3][512][1024] bf16 = 6291456
static const size_t OFF_YS0 = 6619392;                 // [64][512][512] bf16 = 33554432
static const size_t OFF_GX  = 40173824;                // [512][64][1536] f32 or bf16
static const size_t GX_ELEMS = (size_t)512 * 64 * 1536;

__device__ __forceinline__ short f2bf(float x) {       // RNE float->bf16
  uint u = __builtin_bit_cast(uint, x);
  u = u + 0x7fffu + ((u >> 16) & 1u);
  return (short)(u >> 16);
}
__device__ __forceinline__ float bf2f(u16 v) {
  uint u = ((uint)v) << 16;
  return __builtin_bit_cast(float, u);
}

template <int GXBF>
__device__ __forceinline__ float gxld(const void* gx, size_t e) {
  if constexpr (GXBF) return bf2f(((const u16*)gx)[e]);
  else return ((const float*)gx)[e];
}

// ---------------- sentinel: report ws_size via absmax if workspace too small ----------------
__global__ void sentinel_kernel(float* __restrict__ out, float v) {
  out[threadIdx.x] = v;
}

// ---------------- init: zero barrier counters, h0 -> bf16 ----------------
__global__ void init_kernel(const float* __restrict__ h_in, u16* __restrict__ hb,
                            int* __restrict__ bar) {
  int idx = blockIdx.x * 256 + threadIdx.x;
  if (idx < 2) bar[idx] = 0;
  for (int i = idx; i < 2 * 64 * 512; i += gridDim.x * 256) {
    int l = i >> 15, b = (i >> 9) & 63, c = i & 511;
    hb[l * 65536 + b * 512 + c] = (u16)f2bf(h_in[(b * 2 + l) * 512 + c]);
  }
}

// ---------------- W (L,1024,512) f32 -> WT[l][g][n][k] bf16 (k-major) ----------------
__global__ void convert_w_kernel(const float* __restrict__ Wr, const float* __restrict__ Wz,
                                 const float* __restrict__ Wh, u16* __restrict__ WT) {
  int idx = blockIdx.x * 256 + threadIdx.x;       // 6*512*1024 = 3145728 total
  int n = idx & 511, k = (idx >> 9) & 1023, lg = idx >> 19;
  int l = (lg >= 3) ? 1 : 0, g = lg - l * 3;
  const float* W = (g == 0 ? Wr : (g == 1 ? Wz : Wh)) + (size_t)l * 1024 * 512;
  WT[((size_t)lg * 512 + n) * 1024 + k] = (u16)f2bf(W[k * 512 + n]);
}

// ---------------- input projection GEMM: gx[s][b][g*512+n] = A @ WT_g + bias ----------------
// A: [32768][512] rows = b*512+s (f32 x for layer0, bf16 ys0 for layer1)
// WT: layer base [3][512][1024] (k-major, input part k<512)
template <int AF32, int GXBF>
__global__ __launch_bounds__(256) void proj_kernel(
    const void* __restrict__ Araw, const u16* __restrict__ WT,
    const float* __restrict__ br, const float* __restrict__ bz, const float* __restrict__ bh,
    void* __restrict__ gx) {
  __shared__ u16 Alds[128 * 64];
  __shared__ u16 Blds[128 * 64];
  const int tid = threadIdx.x;
  const int wave = tid >> 6, lane = tid & 63;
  const int lan15 = lane & 15, lanhi = lane >> 4;
  const int mb = blockIdx.x & 255, nb = blockIdx.x >> 8;
  const int m0 = mb * 128, n0 = nb * 128;
  const int wm = (wave >> 1) * 64, wn = (wave & 1) * 64;

  const f32x4 z4 = {0.f, 0.f, 0.f, 0.f};
  f32x4 acc[4][4];
#pragma unroll
  for (int i = 0; i < 4; ++i)
#pragma unroll
    for (int j = 0; j < 4; ++j) acc[i][j] = z4;

  for (int kb = 0; kb < 512; kb += 64) {
    __syncthreads();
    if constexpr (AF32) {
      const float* A = (const float*)Araw;
#pragma unroll
      for (int p = 0; p < 4; ++p) {        // stage+convert A tile 128x64 (XOR-swizzled 16B slots)
        int idx = p * 256 + tid;
        int row = idx >> 3, slot = idx & 7;
        const float* src = A + (size_t)(m0 + row) * 512 + kb + slot * 8;
        float4 v0 = *(const float4*)src;
        float4 v1 = *(const float4*)(src + 4);
        u16 tmp[8] = {(u16)f2bf(v0.x), (u16)f2bf(v0.y), (u16)f2bf(v0.z), (u16)f2bf(v0.w),
                      (u16)f2bf(v1.x), (u16)f2bf(v1.y), (u16)f2bf(v1.z), (u16)f2bf(v1.w)};
        *(uint4*)((char*)Alds + row * 128 + ((slot ^ (row & 7)) * 16)) = *(uint4*)tmp;
      }
    } else {
      const u16* A = (const u16*)Araw;
#pragma unroll
      for (int p = 0; p < 4; ++p) {
        int idx = p * 256 + tid;
        int row = idx >> 3, slot = idx & 7;
        uint4 v = *(const uint4*)(A + (size_t)(m0 + row) * 512 + kb + slot * 8);
        *(uint4*)((char*)Alds + row * 128 + ((slot ^ (row & 7)) * 16)) = v;
      }
    }
#pragma unroll
    for (int p = 0; p < 4; ++p) {          // stage B tile 128x64 from WT (n-major rows)
      int idx = p * 256 + tid;
      int row = idx >> 3, slot = idx & 7;
      int ng = n0 + row, g = ng >> 9, nc = ng & 511;
      uint4 v = *(const uint4*)(WT + ((size_t)g * 512 + nc) * 1024 + kb + slot * 8);
      *(uint4*)((char*)Blds + row * 128 + ((slot ^ (row & 7)) * 16)) = v;
    }
    __syncthreads();
#pragma unroll
    for (int ks = 0; ks < 2; ++ks) {
      s16x8 af[4], bfr[4];
#pragma unroll
      for (int f = 0; f < 4; ++f) {
        int rowA = wm + f * 16 + lan15;
        af[f] = *(const s16x8*)((const char*)Alds + rowA * 128 + (((ks * 4 + lanhi) ^ (rowA & 7)) * 16));
        int rowB = wn + f * 16 + lan15;
        bfr[f] = *(const s16x8*)((const char*)Blds + rowB * 128 + (((ks * 4 + lanhi) ^ (rowB & 7)) * 16));
      }
#pragma unroll
      for (int mf = 0; mf < 4; ++mf)
#pragma unroll
        for (int nf = 0; nf < 4; ++nf)
          acc[mf][nf] = MFMA16(af[mf], bfr[nf], acc[mf][nf]);
    }
  }
  // epilogue: D row=batch-row m (4*(lane>>4)+q), col=n (lane&15); add bias; scatter to (s,b,n)
#pragma unroll
  for (int nf = 0; nf < 4; ++nf) {
    int n = n0 + wn + nf * 16 + lan15;
    int g = n >> 9, nc = n & 511;
    float bias = (g == 0 ? br[nc] : (g == 1 ? bz[nc] : bh[nc]));
#pragma unroll
    for (int mf = 0; mf < 4; ++mf) {
#pragma unroll
      for (int q = 0; q < 4; ++q) {
        int m = m0 + wm + mf * 16 + lanhi * 4 + q;
        int s = m & 511, b = m >> 9;
        size_t e = (size_t)(s * 64 + b) * 1536 + n;
        float v = acc[mf][nf][q] + bias;
        if constexpr (GXBF) ((u16*)gx)[e] = (u16)f2bf(v);
        else ((float*)gx)[e] = v;
      }
    }
  }
}

// ---------------- grid barrier (monotonic counter, agent scope) ----------------
__device__ __forceinline__ void gbar(int* bar, int target) {
  __syncthreads();
  if (threadIdx.x == 0) {
    __hip_atomic_fetch_add(bar, 1, __ATOMIC_RELEASE, __HIP_MEMORY_SCOPE_AGENT);
    while (__hip_atomic_load(bar, __ATOMIC_ACQUIRE, __HIP_MEMORY_SCOPE_AGENT) < target)
      __builtin_amdgcn_s_sleep(2);
  }
  __syncthreads();
}

// red buffer addressing: [4 waves][64 cols][64 batches] f32, 16B-slot XOR swizzle on batch
__device__ __forceinline__ int red_off(int w, int c, int b) {
  return ((w * 64 + c) << 6) + ((((b >> 2) ^ (c & 15)) & 15) << 2) + (b & 3);
}

// ---------------- persistent recurrent kernel: 16 WGs x 256 thr, 512 steps ----------------
template <int GXBF>
__global__ __launch_bounds__(256, 1) void recur_kernel(
    const void* __restrict__ gx,     // [512][64][1536] f32 or bf16
    const u16* __restrict__ WT,      // layer base [3][512][1024], recurrent part k in [512,1024)
    const float* __restrict__ h_in,  // [64][2][512]
    u16* __restrict__ hb,            // [2][64][512] bf16 double buffer (this layer)
    u16* __restrict__ rhb,           // [64][512] bf16
    u16* __restrict__ out_bf,        // layer0: ys0 [b][t][c]
    float* __restrict__ out_f32,     // layer1: d_out [b][t][c]
    float* __restrict__ finals,      // d_out + B*S*H, [b][l][c]
    const int layer, int* __restrict__ bar) {
  __shared__ float red[4 * 64 * 64];  // 64 KiB
  const int tid = threadIdx.x;
  const int wave = tid >> 6, lane = tid & 63;
  const int lan15 = lane & 15, lanhi = lane >> 4;
  const int c0 = blockIdx.x * 32;     // owned h-columns [c0, c0+32)
  const int kw = wave * 128;          // K-split per wave
  const int ke8 = lanhi * 8;

  // recurrent-weight fragments -> registers (one-time, ~96 VGPR/lane)
  s16x8 wrz[2][2][4];   // [gate r/z][nfrag][kstep]
  s16x8 whh[2][4];
#pragma unroll
  for (int g = 0; g < 2; ++g)
#pragma unroll
    for (int nf = 0; nf < 2; ++nf)
#pragma unroll
      for (int ks = 0; ks < 4; ++ks)
        wrz[g][nf][ks] = *(const s16x8*)(WT + ((size_t)g * 512 + c0 + nf * 16 + lan15) * 1024 + 512 + kw + ks * 32 + ke8);
#pragma unroll
  for (int nf = 0; nf < 2; ++nf)
#pragma unroll
    for (int ks = 0; ks < 4; ++ks)
      whh[nf][ks] = *(const s16x8*)(WT + ((size_t)2 * 512 + c0 + nf * 16 + lan15) * 1024 + 512 + kw + ks * 32 + ke8);

  // fp32 h state: thread owns batch ob, 8 cols at c0+oc
  const int ob = tid >> 2, oc = (tid & 3) * 8;
  float hown[8];
#pragma unroll
  for (int i = 0; i < 8; ++i) hown[i] = h_in[(ob * 2 + layer) * 512 + c0 + oc + i];

  const f32x4 z4 = {0.f, 0.f, 0.f, 0.f};
  int cur = 0, tgt = 0;

  for (int t = 0; t < 512; ++t) {
    const u16* hcur = hb + cur * (64 * 512);
    // ---- phase 1: [r|z]pre = h @ [Wrh|Wzh] for own 64 gate-cols, K-split 4 waves ----
    f32x4 acc[4][4];
#pragma unroll
    for (int i = 0; i < 4; ++i) { acc[i][0] = z4; acc[i][1] = z4; acc[i][2] = z4; acc[i][3] = z4; }
#pragma unroll
    for (int ks = 0; ks < 4; ++ks) {
      s16x8 af[4];
#pragma unroll
      for (int mf = 0; mf < 4; ++mf)
        af[mf] = *(const s16x8*)(hcur + (mf * 16 + lan15) * 512 + kw + ks * 32 + ke8);
#pragma unroll
      for (int mf = 0; mf < 4; ++mf) {
        acc[mf][0] = MFMA16(af[mf], wrz[0][0][ks], acc[mf][0]);
        acc[mf][1] = MFMA16(af[mf], wrz[0][1][ks], acc[mf][1]);
        acc[mf][2] = MFMA16(af[mf], wrz[1][0][ks], acc[mf][2]);
        acc[mf][3] = MFMA16(af[mf], wrz[1][1][ks], acc[mf][3]);
      }
    }
#pragma unroll
    for (int mf = 0; mf < 4; ++mf)
#pragma unroll
      for (int j = 0; j < 4; ++j)
        *(f32x4*)(red + red_off(wave, j * 16 + lan15, mf * 16 + lanhi * 4)) = acc[mf][j];
    __syncthreads();
    float zg[8];
    {
      size_t gxe = (size_t)(t * 64 + ob) * 1536 + c0 + oc;
      s16x8 rhv;
#pragma unroll
      for (int i = 0; i < 8; ++i) {
        int c = oc + i;
        float rp = gxld<GXBF>(gx, gxe + i);
        float zp = gxld<GXBF>(gx, gxe + 512 + i);
#pragma unroll
        for (int w = 0; w < 4; ++w) {
          rp += red[red_off(w, c, ob)];
          zp += red[red_off(w, 32 + c, ob)];
        }
        float r = 1.f / (1.f + __expf(-rp));
        zg[i] = 1.f / (1.f + __expf(-zp));
        rhv[i] = f2bf(r * hown[i]);
      }
      *(s16x8*)(rhb + ob * 512 + c0 + oc) = rhv;   // publish r*h (own cols)
    }
    tgt += 16; gbar(bar, tgt);
    // ---- phase 2: wpre = (r*h) @ Whh for own 32 cols ----
    f32x4 acc2[4][2];
#pragma unroll
    for (int i = 0; i < 4; ++i) { acc2[i][0] = z4; acc2[i][1] = z4; }
#pragma unroll
    for (int ks = 0; ks < 4; ++ks) {
      s16x8 af[4];
#pragma unroll
      for (int mf = 0; mf < 4; ++mf)
        af[mf] = *(const s16x8*)(rhb + (mf * 16 + lan15) * 512 + kw + ks * 32 + ke8);
#pragma unroll
      for (int mf = 0; mf < 4; ++mf) {
        acc2[mf][0] = MFMA16(af[mf], whh[0][ks], acc2[mf][0]);
        acc2[mf][1] = MFMA16(af[mf], whh[1][ks], acc2[mf][1]);
      }
    }
#pragma unroll
    for (int mf = 0; mf < 4; ++mf)
#pragma unroll
      for (int j = 0; j < 2; ++j)
        *(f32x4*)(red + red_off(wave, j * 16 + lan15, mf * 16 + lanhi * 4)) = acc2[mf][j];
    __syncthreads();
    {
      size_t gxe = (size_t)(t * 64 + ob) * 1536 + 1024 + c0 + oc;
      float hn[8];
#pragma unroll
      for (int i = 0; i < 8; ++i) {
        float wp = 0.f;
#pragma unroll
        for (int w = 0; w < 4; ++w) wp += red[red_off(w, oc + i, ob)];
        float pre = gxld<GXBF>(gx, gxe + i) + wp;
        pre = fminf(15.f, fmaxf(-15.f, pre));     // guard exp overflow -> NaN
        float e = __expf(-2.f * pre);
        float ht = (1.f - e) / (1.f + e);         // tanh
        hn[i] = (1.f - zg[i]) * hown[i] + zg[i] * ht;
        hown[i] = hn[i];
      }
      u16* hnxt = hb + (cur ^ 1) * (64 * 512);
      s16x8 hv;
#pragma unroll
      for (int i = 0; i < 8; ++i) hv[i] = f2bf(hn[i]);
      *(s16x8*)(hnxt + ob * 512 + c0 + oc) = hv;
      if (layer == 0) {
        *(s16x8*)(out_bf + ((size_t)ob * 512 + t) * 512 + c0 + oc) = hv;
      } else {
        float* o = out_f32 + ((size_t)ob * 512 + t) * 512 + c0 + oc;
#pragma unroll
        for (int i = 0; i < 8; ++i) o[i] = hn[i];
      }
      if (t == 511) {
        float* f = finals + (size_t)(ob * 2 + layer) * 512 + c0 + oc;
#pragma unroll
        for (int i = 0; i < 8; ++i) f[i] = hn[i];
      }
    }
    cur ^= 1;
    tgt += 16;
    if (t != 511) gbar(bar, tgt);
  }
}

template <int GXBF>
static void run_all(const float* x, const float* h, const float* Wr, const float* br,
                    const float* Wz, const float* bz, const float* Wh, const float* bh,
                    float* out, char* ws, hipStream_t stream) {
  int* bar   = (int*)(ws + OFF_BAR);
  u16* hbAll = (u16*)(ws + OFF_HB);
  u16* rhb   = (u16*)(ws + OFF_RHB);
  u16* WT    = (u16*)(ws + OFF_WT);
  u16* ys0   = (u16*)(ws + OFF_YS0);
  void* gx   = (void*)(ws + OFF_GX);
  float* finals = out + 16777216;

  init_kernel<<<64, 256, 0, stream>>>(h, hbAll, bar);
  convert_w_kernel<<<12288, 256, 0, stream>>>(Wr, Wz, Wh, WT);

  // layer 0 (A = x, f32)
  proj_kernel<1, GXBF><<<3072, 256, 0, stream>>>(x, WT, br, bz, bh, gx);
  recur_kernel<GXBF><<<16, 256, 0, stream>>>(gx, WT, h, hbAll, rhb, ys0, nullptr, finals, 0, bar + 0);
  // layer 1 (A = ys0, bf16)
  proj_kernel<0, GXBF><<<3072, 256, 0, stream>>>(ys0, WT + (size_t)3 * 512 * 1024,
                                                 br + 512, bz + 512, bh + 512, gx);
  recur_kernel<GXBF><<<16, 256, 0, stream>>>(gx, WT + (size_t)3 * 512 * 1024, h, hbAll + 65536, rhb,
                                             nullptr, out, finals, 1, bar + 1);
}

extern "C" void kernel_launch(void* const* d_in, const int* in_sizes, int n_in,
                              void* d_out, int out_size, void* d_ws, size_t ws_size,
                              hipStream_t stream) {
  const float* x  = (const float*)d_in[0];
  const float* h  = (const float*)d_in[1];
  const float* Wr = (const float*)d_in[2];
  const float* br = (const float*)d_in[3];
  const float* Wz = (const float*)d_in[4];
  const float* bz = (const float*)d_in[5];
  const float* Wh = (const float*)d_in[6];
  const float* bh = (const float*)d_in[7];
  float* out = (float*)d_out;
  char* ws = (char*)d_ws;

  const size_t need_f32 = OFF_GX + GX_ELEMS * 4;   // 241,500,416 B (230.3 MiB)
  const size_t need_bf  = OFF_GX + GX_ELEMS * 2;   // 140,837,120 B (134.3 MiB)

  if (ws_size >= need_f32) {
    run_all<0>(x, h, Wr, br, Wz, bz, Wh, bh, out, ws, stream);
  } else if (ws_size >= need_bf) {
    run_all<1>(x, h, Wr, br, Wz, bz, Wh, bh, out, ws, stream);
  } else {
    // workspace too small for any layout: report its size through absmax
    sentinel_kernel<<<1, 64, 0, stream>>>(out, (float)ws_size);
  }
}

// Round 3
// 10922.680 us; speedup vs baseline: 1.0453x; 1.0453x over previous
//
#include <hip/hip_runtime.h>

typedef unsigned int uint;
typedef unsigned short u16;
typedef short s16x8 __attribute__((ext_vector_type(8)));
typedef float f32x4 __attribute__((ext_vector_type(4)));
typedef uint u32x4 __attribute__((ext_vector_type(4)));

#define MFMA16(a, b, c) __builtin_amdgcn_mfma_f32_16x16x32_bf16((a), (b), (c), 0, 0, 0)

// ---- problem constants ----
// B=64, S=512, D=512, H=512, L=2
// ws layout (bytes)
static const size_t OFF_BAR = 0;                       // 2 ints
static const size_t OFF_HB  = 256;                     // [2 layers][2 bufs][64][512] bf16 = 262144
static const size_t OFF_RHB = 262400;                  // [64][512] bf16 = 65536
static const size_t OFF_WT  = 327936;                  // [2][3][512][1024] bf16 = 6291456
static const size_t OFF_YS0 = 6619392;                 // [64][512][512] bf16 = 33554432
static const size_t OFF_GX  = 40173824;                // [512][64][1536] f32 or bf16
static const size_t GX_ELEMS = (size_t)512 * 64 * 1536;

__device__ __forceinline__ short f2bf(float x) {       // RNE float->bf16
  uint u = __builtin_bit_cast(uint, x);
  u = u + 0x7fffu + ((u >> 16) & 1u);
  return (short)(u >> 16);
}
__device__ __forceinline__ float bf2f(u16 v) {
  uint u = ((uint)v) << 16;
  return __builtin_bit_cast(float, u);
}

// ---- raw 16B memory ops ----
// plain (L2-cacheable) load, issued exactly where placed (asm volatile)
__device__ __forceinline__ u32x4 ld16(const void* p) {
  u32x4 r;
  asm volatile("global_load_dwordx4 %0, %1, off" : "=v"(r) : "v"(p));
  return r;
}
// coherent (cross-XCD visible) load/store: sc0 sc1 -> served at coherence point
__device__ __forceinline__ u32x4 ld16c(const void* p) {
  u32x4 r;
  asm volatile("global_load_dwordx4 %0, %1, off sc0 sc1" : "=v"(r) : "v"(p));
  return r;
}
__device__ __forceinline__ void st16c(void* p, u32x4 v) {
  asm volatile("global_store_dwordx4 %0, %1, off sc0 sc1" :: "v"(p), "v"(v));
}
__device__ __forceinline__ void waitv0() {
  asm volatile("s_waitcnt vmcnt(0)" ::: "memory");
  __builtin_amdgcn_sched_barrier(0);   // rule #18: don't let MFMA hoist past the wait
}

// ---------------- sentinel: report ws_size via absmax if workspace too small ----------------
__global__ void sentinel_kernel(float* __restrict__ out, float v) {
  out[threadIdx.x] = v;
}

// ---------------- init: zero barrier counters, h0 -> bf16 ----------------
__global__ void init_kernel(const float* __restrict__ h_in, u16* __restrict__ hb,
                            int* __restrict__ bar) {
  int idx = blockIdx.x * 256 + threadIdx.x;
  if (idx < 2) bar[idx] = 0;
  for (int i = idx; i < 2 * 64 * 512; i += gridDim.x * 256) {
    int l = i >> 15, b = (i >> 9) & 63, c = i & 511;
    hb[l * 65536 + b * 512 + c] = (u16)f2bf(h_in[(b * 2 + l) * 512 + c]);
  }
}

// ---------------- W (L,1024,512) f32 -> WT[l][g][n][k] bf16 (k-major) ----------------
__global__ void convert_w_kernel(const float* __restrict__ Wr, const float* __restrict__ Wz,
                                 const float* __restrict__ Wh, u16* __restrict__ WT) {
  int idx = blockIdx.x * 256 + threadIdx.x;       // 6*512*1024 = 3145728 total
  int n = idx & 511, k = (idx >> 9) & 1023, lg = idx >> 19;
  int l = (lg >= 3) ? 1 : 0, g = lg - l * 3;
  const float* W = (g == 0 ? Wr : (g == 1 ? Wz : Wh)) + (size_t)l * 1024 * 512;
  WT[((size_t)lg * 512 + n) * 1024 + k] = (u16)f2bf(W[k * 512 + n]);
}

// ---------------- input projection GEMM: gx[s][b][g*512+n] = A @ WT_g + bias ----------------
template <int AF32, int GXBF>
__global__ __launch_bounds__(256) void proj_kernel(
    const void* __restrict__ Araw, const u16* __restrict__ WT,
    const float* __restrict__ br, const float* __restrict__ bz, const float* __restrict__ bh,
    void* __restrict__ gx) {
  __shared__ u16 Alds[128 * 64];
  __shared__ u16 Blds[128 * 64];
  const int tid = threadIdx.x;
  const int wave = tid >> 6, lane = tid & 63;
  const int lan15 = lane & 15, lanhi = lane >> 4;
  const int mb = blockIdx.x & 255, nb = blockIdx.x >> 8;
  const int m0 = mb * 128, n0 = nb * 128;
  const int wm = (wave >> 1) * 64, wn = (wave & 1) * 64;

  const f32x4 z4 = {0.f, 0.f, 0.f, 0.f};
  f32x4 acc[4][4];
#pragma unroll
  for (int i = 0; i < 4; ++i)
#pragma unroll
    for (int j = 0; j < 4; ++j) acc[i][j] = z4;

  for (int kb = 0; kb < 512; kb += 64) {
    __syncthreads();
    if constexpr (AF32) {
      const float* A = (const float*)Araw;
#pragma unroll
      for (int p = 0; p < 4; ++p) {        // stage+convert A tile 128x64 (XOR-swizzled 16B slots)
        int idx = p * 256 + tid;
        int row = idx >> 3, slot = idx & 7;
        const float* src = A + (size_t)(m0 + row) * 512 + kb + slot * 8;
        float4 v0 = *(const float4*)src;
        float4 v1 = *(const float4*)(src + 4);
        u16 tmp[8] = {(u16)f2bf(v0.x), (u16)f2bf(v0.y), (u16)f2bf(v0.z), (u16)f2bf(v0.w),
                      (u16)f2bf(v1.x), (u16)f2bf(v1.y), (u16)f2bf(v1.z), (u16)f2bf(v1.w)};
        *(uint4*)((char*)Alds + row * 128 + ((slot ^ (row & 7)) * 16)) = *(uint4*)tmp;
      }
    } else {
      const u16* A = (const u16*)Araw;
#pragma unroll
      for (int p = 0; p < 4; ++p) {
        int idx = p * 256 + tid;
        int row = idx >> 3, slot = idx & 7;
        uint4 v = *(const uint4*)(A + (size_t)(m0 + row) * 512 + kb + slot * 8);
        *(uint4*)((char*)Alds + row * 128 + ((slot ^ (row & 7)) * 16)) = v;
      }
    }
#pragma unroll
    for (int p = 0; p < 4; ++p) {          // stage B tile 128x64 from WT (n-major rows)
      int idx = p * 256 + tid;
      int row = idx >> 3, slot = idx & 7;
      int ng = n0 + row, g = ng >> 9, nc = ng & 511;
      uint4 v = *(const uint4*)(WT + ((size_t)g * 512 + nc) * 1024 + kb + slot * 8);
      *(uint4*)((char*)Blds + row * 128 + ((slot ^ (row & 7)) * 16)) = v;
    }
    __syncthreads();
#pragma unroll
    for (int ks = 0; ks < 2; ++ks) {
      s16x8 af[4], bfr[4];
#pragma unroll
      for (int f = 0; f < 4; ++f) {
        int rowA = wm + f * 16 + lan15;
        af[f] = *(const s16x8*)((const char*)Alds + rowA * 128 + (((ks * 4 + lanhi) ^ (rowA & 7)) * 16));
        int rowB = wn + f * 16 + lan15;
        bfr[f] = *(const s16x8*)((const char*)Blds + rowB * 128 + (((ks * 4 + lanhi) ^ (rowB & 7)) * 16));
      }
#pragma unroll
      for (int mf = 0; mf < 4; ++mf)
#pragma unroll
        for (int nf = 0; nf < 4; ++nf)
          acc[mf][nf] = MFMA16(af[mf], bfr[nf], acc[mf][nf]);
    }
  }
#pragma unroll
  for (int nf = 0; nf < 4; ++nf) {
    int n = n0 + wn + nf * 16 + lan15;
    int g = n >> 9, nc = n & 511;
    float bias = (g == 0 ? br[nc] : (g == 1 ? bz[nc] : bh[nc]));
#pragma unroll
    for (int mf = 0; mf < 4; ++mf) {
#pragma unroll
      for (int q = 0; q < 4; ++q) {
        int m = m0 + wm + mf * 16 + lanhi * 4 + q;
        int s = m & 511, b = m >> 9;
        size_t e = (size_t)(s * 64 + b) * 1536 + n;
        float v = acc[mf][nf][q] + bias;
        if constexpr (GXBF) ((u16*)gx)[e] = (u16)f2bf(v);
        else ((float*)gx)[e] = v;
      }
    }
  }
}

// ---------------- grid barrier: relaxed atomics, no cache-wide maintenance ----------------
// Coherence of exchanged data is handled by sc0/sc1 loads/stores + vmcnt(0) before arrival.
__device__ __forceinline__ void gbar(int* bar, int target) {
  asm volatile("s_waitcnt vmcnt(0)" ::: "memory");   // my coherent stores are visible
  __syncthreads();
  if (threadIdx.x == 0) {
    __hip_atomic_fetch_add(bar, 1, __ATOMIC_RELAXED, __HIP_MEMORY_SCOPE_AGENT);
    while (__hip_atomic_load(bar, __ATOMIC_RELAXED, __HIP_MEMORY_SCOPE_AGENT) < target)
      __builtin_amdgcn_s_sleep(1);
  }
  __syncthreads();
}

// red buffer addressing: [4 waves][64 cols][64 batches] f32, 16B-slot XOR swizzle on batch
__device__ __forceinline__ int red_off(int w, int c, int b) {
  return ((w * 64 + c) << 6) + ((((b >> 2) ^ (c & 15)) & 15) << 2) + (b & 3);
}

template <int GXBF>
__device__ __forceinline__ void unpack8(const u32x4& a, const u32x4& b, float o[8]) {
  if constexpr (GXBF) {
    const u16* p = (const u16*)&a;
#pragma unroll
    for (int i = 0; i < 8; ++i) o[i] = bf2f(p[i]);
  } else {
    const float* pa = (const float*)&a;
    const float* pb = (const float*)&b;
#pragma unroll
    for (int i = 0; i < 4; ++i) { o[i] = pa[i]; o[4 + i] = pb[i]; }
  }
}

// ---------------- persistent recurrent kernel: 16 WGs x 256 thr, 512 steps ----------------
template <int GXBF>
__global__ __launch_bounds__(256, 1) void recur_kernel(
    const void* __restrict__ gx,     // [512][64][1536] f32 or bf16
    const u16* __restrict__ WT,      // layer base [3][512][1024], recurrent part k in [512,1024)
    const float* __restrict__ h_in,  // [64][2][512]
    u16* __restrict__ hb,            // [2][64][512] bf16 double buffer (this layer)
    u16* __restrict__ rhb,           // [64][512] bf16
    u16* __restrict__ out_bf,        // layer0: ys0 [b][t][c]
    float* __restrict__ out_f32,     // layer1: d_out [b][t][c]
    float* __restrict__ finals,      // d_out + B*S*H, [b][l][c]
    const int layer, int* __restrict__ bar) {
  __shared__ float red[4 * 64 * 64];  // 64 KiB
  const int tid = threadIdx.x;
  const int wave = tid >> 6, lane = tid & 63;
  const int lan15 = lane & 15, lanhi = lane >> 4;
  const int c0 = blockIdx.x * 32;     // owned h-columns [c0, c0+32)
  const int kw = wave * 128;          // K-split per wave
  const int ke8 = lanhi * 8;
  const int ES = GXBF ? 2 : 4;

  // recurrent-weight fragments -> registers (one-time)
  s16x8 wrz[2][2][4];   // [gate r/z][nfrag][kstep]
  s16x8 whh[2][4];
#pragma unroll
  for (int g = 0; g < 2; ++g)
#pragma unroll
    for (int nf = 0; nf < 2; ++nf)
#pragma unroll
      for (int ks = 0; ks < 4; ++ks)
        wrz[g][nf][ks] = *(const s16x8*)(WT + ((size_t)g * 512 + c0 + nf * 16 + lan15) * 1024 + 512 + kw + ks * 32 + ke8);
#pragma unroll
  for (int nf = 0; nf < 2; ++nf)
#pragma unroll
    for (int ks = 0; ks < 4; ++ks)
      whh[nf][ks] = *(const s16x8*)(WT + ((size_t)2 * 512 + c0 + nf * 16 + lan15) * 1024 + 512 + kw + ks * 32 + ke8);

  // fp32 h state: thread owns batch ob, 8 cols at c0+oc
  const int ob = tid >> 2, oc = (tid & 3) * 8;
  float hown[8];
#pragma unroll
  for (int i = 0; i < 8; ++i) hown[i] = h_in[(ob * 2 + layer) * 512 + c0 + oc + i];

  const f32x4 z4 = {0.f, 0.f, 0.f, 0.f};
  int cur = 0, tgt = 0;

  for (int t = 0; t < 512; ++t) {
    const u16* hcur = hb + cur * (64 * 512);
    // ---- issue this step's gx loads up front (r,z for p1; h for p2) ----
    const char* gxp = (const char*)gx + ((size_t)(t * 64 + ob) * 1536 + c0 + oc) * ES;
    u32x4 g_r0 = {0, 0, 0, 0}, g_r1 = {0, 0, 0, 0};
    u32x4 g_z0 = {0, 0, 0, 0}, g_z1 = {0, 0, 0, 0};
    u32x4 g_h0 = {0, 0, 0, 0}, g_h1 = {0, 0, 0, 0};
    if constexpr (GXBF) {
      g_r0 = ld16(gxp);
      g_z0 = ld16(gxp + 512 * ES);
      g_h0 = ld16(gxp + 1024 * ES);
    } else {
      g_r0 = ld16(gxp);                 g_r1 = ld16(gxp + 16);
      g_z0 = ld16(gxp + 512 * ES);      g_z1 = ld16(gxp + 512 * ES + 16);
      g_h0 = ld16(gxp + 1024 * ES);     g_h1 = ld16(gxp + 1024 * ES + 16);
    }
    // ---- phase 1: [r|z]pre = h @ [Wrh|Wzh], K-split 4 waves ----
    u32x4 hl[4][4];
#pragma unroll
    for (int ks = 0; ks < 4; ++ks)
#pragma unroll
      for (int mf = 0; mf < 4; ++mf)
        hl[ks][mf] = ld16c(hcur + (mf * 16 + lan15) * 512 + kw + ks * 32 + ke8);
    waitv0();
    f32x4 acc[4][4];
#pragma unroll
    for (int i = 0; i < 4; ++i) { acc[i][0] = z4; acc[i][1] = z4; acc[i][2] = z4; acc[i][3] = z4; }
#pragma unroll
    for (int ks = 0; ks < 4; ++ks) {
#pragma unroll
      for (int mf = 0; mf < 4; ++mf) {
        s16x8 af = __builtin_bit_cast(s16x8, hl[ks][mf]);
        acc[mf][0] = MFMA16(af, wrz[0][0][ks], acc[mf][0]);
        acc[mf][1] = MFMA16(af, wrz[0][1][ks], acc[mf][1]);
        acc[mf][2] = MFMA16(af, wrz[1][0][ks], acc[mf][2]);
        acc[mf][3] = MFMA16(af, wrz[1][1][ks], acc[mf][3]);
      }
    }
#pragma unroll
    for (int mf = 0; mf < 4; ++mf)
#pragma unroll
      for (int j = 0; j < 4; ++j)
        *(f32x4*)(red + red_off(wave, j * 16 + lan15, mf * 16 + lanhi * 4)) = acc[mf][j];
    __syncthreads();
    float zg[8];
    {
      float grf[8], gzf[8];
      unpack8<GXBF>(g_r0, g_r1, grf);
      unpack8<GXBF>(g_z0, g_z1, gzf);
      s16x8 rhv;
#pragma unroll
      for (int i = 0; i < 8; ++i) {
        int c = oc + i;
        float rp = grf[i];
        float zp = gzf[i];
#pragma unroll
        for (int w = 0; w < 4; ++w) {
          rp += red[red_off(w, c, ob)];
          zp += red[red_off(w, 32 + c, ob)];
        }
        float r = 1.f / (1.f + __expf(-rp));
        zg[i] = 1.f / (1.f + __expf(-zp));
        rhv[i] = f2bf(r * hown[i]);
      }
      st16c(rhb + ob * 512 + c0 + oc, __builtin_bit_cast(u32x4, rhv));   // publish r*h
    }
    tgt += 16; gbar(bar, tgt);
    // ---- phase 2: wpre = (r*h) @ Whh for own 32 cols ----
    u32x4 rl[4][4];
#pragma unroll
    for (int ks = 0; ks < 4; ++ks)
#pragma unroll
      for (int mf = 0; mf < 4; ++mf)
        rl[ks][mf] = ld16c(rhb + (mf * 16 + lan15) * 512 + kw + ks * 32 + ke8);
    waitv0();
    f32x4 acc2[4][2];
#pragma unroll
    for (int i = 0; i < 4; ++i) { acc2[i][0] = z4; acc2[i][1] = z4; }
#pragma unroll
    for (int ks = 0; ks < 4; ++ks) {
#pragma unroll
      for (int mf = 0; mf < 4; ++mf) {
        s16x8 af = __builtin_bit_cast(s16x8, rl[ks][mf]);
        acc2[mf][0] = MFMA16(af, whh[0][ks], acc2[mf][0]);
        acc2[mf][1] = MFMA16(af, whh[1][ks], acc2[mf][1]);
      }
    }
#pragma unroll
    for (int mf = 0; mf < 4; ++mf)
#pragma unroll
      for (int j = 0; j < 2; ++j)
        *(f32x4*)(red + red_off(wave, j * 16 + lan15, mf * 16 + lanhi * 4)) = acc2[mf][j];
    __syncthreads();
    {
      float ghf[8];
      unpack8<GXBF>(g_h0, g_h1, ghf);
      float hn[8];
#pragma unroll
      for (int i = 0; i < 8; ++i) {
        float wp = 0.f;
#pragma unroll
        for (int w = 0; w < 4; ++w) wp += red[red_off(w, oc + i, ob)];
        float pre = ghf[i] + wp;
        pre = fminf(15.f, fmaxf(-15.f, pre));     // guard exp overflow -> NaN
        float e = __expf(-2.f * pre);
        float ht = (1.f - e) / (1.f + e);         // tanh
        hn[i] = (1.f - zg[i]) * hown[i] + zg[i] * ht;
        hown[i] = hn[i];
      }
      u16* hnxt = hb + (cur ^ 1) * (64 * 512);
      s16x8 hv;
#pragma unroll
      for (int i = 0; i < 8; ++i) hv[i] = f2bf(hn[i]);
      st16c(hnxt + ob * 512 + c0 + oc, __builtin_bit_cast(u32x4, hv));
      if (layer == 0) {
        *(s16x8*)(out_bf + ((size_t)ob * 512 + t) * 512 + c0 + oc) = hv;
      } else {
        float* o = out_f32 + ((size_t)ob * 512 + t) * 512 + c0 + oc;
#pragma unroll
        for (int i = 0; i < 8; ++i) o[i] = hn[i];
      }
      if (t == 511) {
        float* f = finals + (size_t)(ob * 2 + layer) * 512 + c0 + oc;
#pragma unroll
        for (int i = 0; i < 8; ++i) f[i] = hn[i];
      }
    }
    cur ^= 1;
    tgt += 16;
    if (t != 511) gbar(bar, tgt);
  }
}

template <int GXBF>
static void run_all(const float* x, const float* h, const float* Wr, const float* br,
                    const float* Wz, const float* bz, const float* Wh, const float* bh,
                    float* out, char* ws, hipStream_t stream) {
  int* bar   = (int*)(ws + OFF_BAR);
  u16* hbAll = (u16*)(ws + OFF_HB);
  u16* rhb   = (u16*)(ws + OFF_RHB);
  u16* WT    = (u16*)(ws + OFF_WT);
  u16* ys0   = (u16*)(ws + OFF_YS0);
  void* gx   = (void*)(ws + OFF_GX);
  float* finals = out + 16777216;

  init_kernel<<<64, 256, 0, stream>>>(h, hbAll, bar);
  convert_w_kernel<<<12288, 256, 0, stream>>>(Wr, Wz, Wh, WT);

  // layer 0 (A = x, f32)
  proj_kernel<1, GXBF><<<3072, 256, 0, stream>>>(x, WT, br, bz, bh, gx);
  recur_kernel<GXBF><<<16, 256, 0, stream>>>(gx, WT, h, hbAll, rhb, ys0, nullptr, finals, 0, bar + 0);
  // layer 1 (A = ys0, bf16)
  proj_kernel<0, GXBF><<<3072, 256, 0, stream>>>(ys0, WT + (size_t)3 * 512 * 1024,
                                                 br + 512, bz + 512, bh + 512, gx);
  recur_kernel<GXBF><<<16, 256, 0, stream>>>(gx, WT + (size_t)3 * 512 * 1024, h, hbAll + 65536, rhb,
                                             nullptr, out, finals, 1, bar + 1);
}

extern "C" void kernel_launch(void* const* d_in, const int* in_sizes, int n_in,
                              void* d_out, int out_size, void* d_ws, size_t ws_size,
                              hipStream_t stream) {
  const float* x  = (const float*)d_in[0];
  const float* h  = (const float*)d_in[1];
  const float* Wr = (const float*)d_in[2];
  const float* br = (const float*)d_in[3];
  const float* Wz = (const float*)d_in[4];
  const float* bz = (const float*)d_in[5];
  const float* Wh = (const float*)d_in[6];
  const float* bh = (const float*)d_in[7];
  float* out = (float*)d_out;
  char* ws = (char*)d_ws;

  const size_t need_f32 = OFF_GX + GX_ELEMS * 4;   // 241,500,416 B (230.3 MiB)
  const size_t need_bf  = OFF_GX + GX_ELEMS * 2;   // 140,837,120 B (134.3 MiB)

  if (ws_size >= need_f32) {
    run_all<0>(x, h, Wr, br, Wz, bz, Wh, bh, out, ws, stream);
  } else if (ws_size >= need_bf) {
    run_all<1>(x, h, Wr, br, Wz, bz, Wh, bh, out, ws, stream);
  } else {
    sentinel_kernel<<<1, 64, 0, stream>>>(out, (float)ws_size);
  }
}

// Round 6
// 8857.539 us; speedup vs baseline: 1.2891x; 1.2332x over previous
//
#include <hip/hip_runtime.h>

typedef unsigned int uint;
typedef unsigned short u16;
typedef short s16x8 __attribute__((ext_vector_type(8)));
typedef float f32x4 __attribute__((ext_vector_type(4)));
typedef uint u32x4 __attribute__((ext_vector_type(4)));

#define MFMA16(a, b, c) __builtin_amdgcn_mfma_f32_16x16x32_bf16((a), (b), (c), 0, 0, 0)

// ---- problem constants ----
// B=64, S=512, D=512, H=512, L=2
// ws layout (bytes).  sync region = 1024 B:
//   int[0]        bar layer0   (own 128B line, L2-scope atomics only)
//   int[32]       bar layer1   (own 128B line)
//   int[64..71]   claim layer0 (L3-scope line, shared with below)
//   int[72..79]   claim layer1
//   int[80],[81]  winner layer0/1
static const size_t OFF_SYNC = 0;                      // 1024 B
static const size_t OFF_HB  = 1024;                    // [2 layers][2 bufs][64][512] bf16 = 262144
static const size_t OFF_RHB = 263168;                  // [64][512] bf16 = 65536
static const size_t OFF_WT  = 328704;                  // [2][3][512][1024] bf16 = 6291456
static const size_t OFF_YS0 = 6620160;                 // [64][512][512] bf16 = 33554432
static const size_t OFF_GX  = 40174592;                // [512][64][1536] f32 or bf16
static const size_t GX_ELEMS = (size_t)512 * 64 * 1536;

__device__ __forceinline__ short f2bf(float x) {       // RNE float->bf16
  uint u = __builtin_bit_cast(uint, x);
  u = u + 0x7fffu + ((u >> 16) & 1u);
  return (short)(u >> 16);
}
__device__ __forceinline__ float bf2f(u16 v) {
  uint u = ((uint)v) << 16;
  return __builtin_bit_cast(float, u);
}

// ---- raw 16B memory ops (plain scope: L1 + XCD-L2; co-located workers share the L2) ----
__device__ __forceinline__ u32x4 ld16(const void* p) {
  u32x4 r;
  asm volatile("global_load_dwordx4 %0, %1, off" : "=v"(r) : "v"(p));
  return r;
}
__device__ __forceinline__ void st16(void* p, u32x4 v) {
  asm volatile("global_store_dwordx4 %0, %1, off" :: "v"(p), "v"(v));
}
__device__ __forceinline__ void waitv0() {
  asm volatile("s_waitcnt vmcnt(0)" ::: "memory");
  __builtin_amdgcn_sched_barrier(0);   // rule #18
}

// ---------------- sentinel ----------------
__global__ void sentinel_kernel(float* __restrict__ out, float v) {
  out[threadIdx.x] = v;
}

// ---------------- init: sync words, h0 -> bf16 ----------------
__global__ void init_kernel(const float* __restrict__ h_in, u16* __restrict__ hb,
                            int* __restrict__ sync) {
  int idx = blockIdx.x * 256 + threadIdx.x;
  if (idx < 256) sync[idx] = (idx == 80 || idx == 81) ? -1 : 0;   // winners = -1
  for (int i = idx; i < 2 * 64 * 512; i += gridDim.x * 256) {
    int l = i >> 15, b = (i >> 9) & 63, c = i & 511;
    hb[l * 65536 + b * 512 + c] = (u16)f2bf(h_in[(b * 2 + l) * 512 + c]);
  }
}

// ---------------- W (L,1024,512) f32 -> WT[l][g][n][k] bf16 (k-major) ----------------
__global__ void convert_w_kernel(const float* __restrict__ Wr, const float* __restrict__ Wz,
                                 const float* __restrict__ Wh, u16* __restrict__ WT) {
  int idx = blockIdx.x * 256 + threadIdx.x;       // 6*512*1024 = 3145728 total
  int n = idx & 511, k = (idx >> 9) & 1023, lg = idx >> 19;
  int l = (lg >= 3) ? 1 : 0, g = lg - l * 3;
  const float* W = (g == 0 ? Wr : (g == 1 ? Wz : Wh)) + (size_t)l * 1024 * 512;
  WT[((size_t)lg * 512 + n) * 1024 + k] = (u16)f2bf(W[k * 512 + n]);
}

// ---------------- input projection GEMM: gx[s][b][g*512+n] = A @ WT_g + bias ----------------
template <int AF32, int GXBF>
__global__ __launch_bounds__(256) void proj_kernel(
    const void* __restrict__ Araw, const u16* __restrict__ WT,
    const float* __restrict__ br, const float* __restrict__ bz, const float* __restrict__ bh,
    void* __restrict__ gx) {
  __shared__ u16 Alds[128 * 64];
  __shared__ u16 Blds[128 * 64];
  const int tid = threadIdx.x;
  const int wave = tid >> 6, lane = tid & 63;
  const int lan15 = lane & 15, lanhi = lane >> 4;
  const int mb = blockIdx.x & 255, nb = blockIdx.x >> 8;
  const int m0 = mb * 128, n0 = nb * 128;
  const int wm = (wave >> 1) * 64, wn = (wave & 1) * 64;

  const f32x4 z4 = {0.f, 0.f, 0.f, 0.f};
  f32x4 acc[4][4];
#pragma unroll
  for (int i = 0; i < 4; ++i)
#pragma unroll
    for (int j = 0; j < 4; ++j) acc[i][j] = z4;

  for (int kb = 0; kb < 512; kb += 64) {
    __syncthreads();
    if constexpr (AF32) {
      const float* A = (const float*)Araw;
#pragma unroll
      for (int p = 0; p < 4; ++p) {        // stage+convert A tile 128x64 (XOR-swizzled 16B slots)
        int idx = p * 256 + tid;
        int row = idx >> 3, slot = idx & 7;
        const float* src = A + (size_t)(m0 + row) * 512 + kb + slot * 8;
        float4 v0 = *(const float4*)src;
        float4 v1 = *(const float4*)(src + 4);
        u16 tmp[8] = {(u16)f2bf(v0.x), (u16)f2bf(v0.y), (u16)f2bf(v0.z), (u16)f2bf(v0.w),
                      (u16)f2bf(v1.x), (u16)f2bf(v1.y), (u16)f2bf(v1.z), (u16)f2bf(v1.w)};
        *(uint4*)((char*)Alds + row * 128 + ((slot ^ (row & 7)) * 16)) = *(uint4*)tmp;
      }
    } else {
      const u16* A = (const u16*)Araw;
#pragma unroll
      for (int p = 0; p < 4; ++p) {
        int idx = p * 256 + tid;
        int row = idx >> 3, slot = idx & 7;
        uint4 v = *(const uint4*)(A + (size_t)(m0 + row) * 512 + kb + slot * 8);
        *(uint4*)((char*)Alds + row * 128 + ((slot ^ (row & 7)) * 16)) = v;
      }
    }
#pragma unroll
    for (int p = 0; p < 4; ++p) {          // stage B tile 128x64 from WT (n-major rows)
      int idx = p * 256 + tid;
      int row = idx >> 3, slot = idx & 7;
      int ng = n0 + row, g = ng >> 9, nc = ng & 511;
      uint4 v = *(const uint4*)(WT + ((size_t)g * 512 + nc) * 1024 + kb + slot * 8);
      *(uint4*)((char*)Blds + row * 128 + ((slot ^ (row & 7)) * 16)) = v;
    }
    __syncthreads();
#pragma unroll
    for (int ks = 0; ks < 2; ++ks) {
      s16x8 af[4], bfr[4];
#pragma unroll
      for (int f = 0; f < 4; ++f) {
        int rowA = wm + f * 16 + lan15;
        af[f] = *(const s16x8*)((const char*)Alds + rowA * 128 + (((ks * 4 + lanhi) ^ (rowA & 7)) * 16));
        int rowB = wn + f * 16 + lan15;
        bfr[f] = *(const s16x8*)((const char*)Blds + rowB * 128 + (((ks * 4 + lanhi) ^ (rowB & 7)) * 16));
      }
#pragma unroll
      for (int mf = 0; mf < 4; ++mf)
#pragma unroll
        for (int nf = 0; nf < 4; ++nf)
          acc[mf][nf] = MFMA16(af[mf], bfr[nf], acc[mf][nf]);
    }
  }
#pragma unroll
  for (int nf = 0; nf < 4; ++nf) {
    int n = n0 + wn + nf * 16 + lan15;
    int g = n >> 9, nc = n & 511;
    float bias = (g == 0 ? br[nc] : (g == 1 ? bz[nc] : bh[nc]));
#pragma unroll
    for (int mf = 0; mf < 4; ++mf) {
#pragma unroll
      for (int q = 0; q < 4; ++q) {
        int m = m0 + wm + mf * 16 + lanhi * 4 + q;
        int s = m & 511, b = m >> 9;
        size_t e = (size_t)(s * 64 + b) * 1536 + n;
        float v = acc[mf][nf][q] + bias;
        if constexpr (GXBF) ((u16*)gx)[e] = (u16)f2bf(v);
        else ((float*)gx)[e] = v;
      }
    }
  }
}

// ---------------- XCD-local barrier: L2-executed atomics (arrive + returning-atomic poll) ----
// Plain-scope atomics execute in the issuing XCD's L2; all workers are co-located, so they
// hit the SAME L2 line. Poll uses atomic_add(0) with sc0 (= return old value) -> bypasses L1
// by construction. Counter is monotonic across phases (target += 16 each phase).
__device__ __forceinline__ void gbarA(int* bar, int target) {
  asm volatile("s_waitcnt vmcnt(0)" ::: "memory");   // my exchange stores are in L2
  __syncthreads();                                   // whole WG's stores are in L2
  if (threadIdx.x == 0) {
    int one = 1;
    asm volatile("global_atomic_add %0, %1, off" :: "v"(bar), "v"(one) : "memory");
    int v, zero = 0, iter = 0;
    do {
      __builtin_amdgcn_s_sleep(2);
      asm volatile("global_atomic_add %0, %1, %2, off sc0\n\ts_waitcnt vmcnt(0)"
                   : "=v"(v) : "v"(bar), "v"(zero) : "memory");
    } while (v < target && ++iter < (1 << 17));      // watchdog: fail wrong, not hung
  }
  __syncthreads();
  __builtin_amdgcn_sched_barrier(0);
}

// red buffer addressing: [4 waves][64 cols][64 batches] f32, 16B-slot XOR swizzle on batch
__device__ __forceinline__ int red_off(int w, int c, int b) {
  return ((w * 64 + c) << 6) + ((((b >> 2) ^ (c & 15)) & 15) << 2) + (b & 3);
}

template <int GXBF>
__device__ __forceinline__ void unpack8(const u32x4& a, const u32x4& b, float o[8]) {
  if constexpr (GXBF) {
    const u16* p = (const u16*)&a;
#pragma unroll
    for (int i = 0; i < 8; ++i) o[i] = bf2f(p[i]);
  } else {
    const float* pa = (const float*)&a;
    const float* pb = (const float*)&b;
#pragma unroll
    for (int i = 0; i < 4; ++i) { o[i] = pa[i]; o[4 + i] = pb[i]; }
  }
}

// ---------------- persistent recurrent kernel ----------------
// Launched with 256 WGs; 16 workers elected onto ONE XCD (shared-L2 coherence domain).
template <int GXBF>
__global__ __launch_bounds__(256, 1) void recur_kernel(
    const void* __restrict__ gx,     // [512][64][1536] f32 or bf16
    const u16* __restrict__ WT,      // layer base [3][512][1024], recurrent part k in [512,1024)
    const float* __restrict__ h_in,  // [64][2][512]
    u16* __restrict__ hb,            // [2][64][512] bf16 double buffer (this layer)
    u16* __restrict__ rhb,           // [64][512] bf16
    u16* __restrict__ out_bf,        // layer0: ys0 [b][t][c]
    float* __restrict__ out_f32,     // layer1: d_out [b][t][c]
    float* __restrict__ finals,      // d_out + B*S*H, [b][l][c]
    const int layer, int* __restrict__ bar,
    int* __restrict__ claim, int* __restrict__ winner) {
  __shared__ float red[4 * 64 * 64];  // 64 KiB
  __shared__ int s_slot;

  // ---- election (L3-scope compiler atomics, proven R3/R5): first 16 of winning XCD ----
  if (threadIdx.x == 0) {
    int xcc;
    asm volatile("s_getreg_b32 %0, hwreg(HW_REG_XCC_ID)" : "=s"(xcc));
    xcc &= 7;
    int slot = __hip_atomic_fetch_add(&claim[xcc], 1, __ATOMIC_RELAXED, __HIP_MEMORY_SCOPE_AGENT);
    int my = -1;
    if (slot < 16) {
      if (slot == 15) {
        int expected = -1;
        __hip_atomic_compare_exchange_strong(winner, &expected, xcc, __ATOMIC_RELAXED,
                                             __ATOMIC_RELAXED, __HIP_MEMORY_SCOPE_AGENT);
      }
      int w, it = 0;
      do {
        __builtin_amdgcn_s_sleep(8);
        w = __hip_atomic_load(winner, __ATOMIC_RELAXED, __HIP_MEMORY_SCOPE_AGENT);
      } while (w < 0 && ++it < (1 << 22));   // watchdog
      my = (w == xcc) ? slot : -1;
    }
    s_slot = my;
  }
  __syncthreads();
  const int slot = s_slot;
  if (slot < 0) return;

  const int tid = threadIdx.x;
  const int wave = tid >> 6, lane = tid & 63;
  const int lan15 = lane & 15, lanhi = lane >> 4;
  const int c0 = slot * 32;           // owned h-columns [c0, c0+32)
  const int kw = wave * 128;          // K-split per wave
  const int ke8 = lanhi * 8;
  const int ES = GXBF ? 2 : 4;

  // recurrent-weight fragments -> registers (one-time)
  s16x8 wrz[2][2][4];   // [gate r/z][nfrag][kstep]
  s16x8 whh[2][4];
#pragma unroll
  for (int g = 0; g < 2; ++g)
#pragma unroll
    for (int nf = 0; nf < 2; ++nf)
#pragma unroll
      for (int ks = 0; ks < 4; ++ks)
        wrz[g][nf][ks] = *(const s16x8*)(WT + ((size_t)g * 512 + c0 + nf * 16 + lan15) * 1024 + 512 + kw + ks * 32 + ke8);
#pragma unroll
  for (int nf = 0; nf < 2; ++nf)
#pragma unroll
    for (int ks = 0; ks < 4; ++ks)
      whh[nf][ks] = *(const s16x8*)(WT + ((size_t)2 * 512 + c0 + nf * 16 + lan15) * 1024 + 512 + kw + ks * 32 + ke8);

  // fp32 h state: thread owns batch ob, 8 cols at c0+oc
  const int ob = tid >> 2, oc = (tid & 3) * 8;
  float hown[8];
#pragma unroll
  for (int i = 0; i < 8; ++i) hown[i] = h_in[(ob * 2 + layer) * 512 + c0 + oc + i];

  const f32x4 z4 = {0.f, 0.f, 0.f, 0.f};
  int cur = 0, tgt = 0;

  for (int t = 0; t < 512; ++t) {
    const u16* hcur = hb + cur * (64 * 512);
    // ---- phase 1: h loads first (plain, shared L2), then gx (HBM), counted wait ----
    __builtin_amdgcn_sched_barrier(0);
    u32x4 hl[4][4];
#pragma unroll
    for (int ks = 0; ks < 4; ++ks)
#pragma unroll
      for (int mf = 0; mf < 4; ++mf)
        hl[ks][mf] = ld16(hcur + (mf * 16 + lan15) * 512 + kw + ks * 32 + ke8);
    const char* gxp = (const char*)gx + ((size_t)(t * 64 + ob) * 1536 + c0 + oc) * ES;
    u32x4 g_r0 = {0, 0, 0, 0}, g_r1 = {0, 0, 0, 0};
    u32x4 g_z0 = {0, 0, 0, 0}, g_z1 = {0, 0, 0, 0};
    u32x4 g_h0 = {0, 0, 0, 0}, g_h1 = {0, 0, 0, 0};
    if constexpr (GXBF) {
      g_r0 = ld16(gxp);
      g_z0 = ld16(gxp + 512 * ES);
      g_h0 = ld16(gxp + 1024 * ES);
      asm volatile("s_waitcnt vmcnt(3)" ::: "memory");   // h loads done, gx in flight
    } else {
      g_r0 = ld16(gxp);                 g_r1 = ld16(gxp + 16);
      g_z0 = ld16(gxp + 512 * ES);      g_z1 = ld16(gxp + 512 * ES + 16);
      g_h0 = ld16(gxp + 1024 * ES);     g_h1 = ld16(gxp + 1024 * ES + 16);
      asm volatile("s_waitcnt vmcnt(6)" ::: "memory");   // h loads done, gx in flight
    }
    __builtin_amdgcn_sched_barrier(0);
    f32x4 acc[4][4];
#pragma unroll
    for (int i = 0; i < 4; ++i) { acc[i][0] = z4; acc[i][1] = z4; acc[i][2] = z4; acc[i][3] = z4; }
#pragma unroll
    for (int ks = 0; ks < 4; ++ks) {
#pragma unroll
      for (int mf = 0; mf < 4; ++mf) {
        s16x8 af = __builtin_bit_cast(s16x8, hl[ks][mf]);
        acc[mf][0] = MFMA16(af, wrz[0][0][ks], acc[mf][0]);
        acc[mf][1] = MFMA16(af, wrz[0][1][ks], acc[mf][1]);
        acc[mf][2] = MFMA16(af, wrz[1][0][ks], acc[mf][2]);
        acc[mf][3] = MFMA16(af, wrz[1][1][ks], acc[mf][3]);
      }
    }
#pragma unroll
    for (int mf = 0; mf < 4; ++mf)
#pragma unroll
      for (int j = 0; j < 4; ++j)
        *(f32x4*)(red + red_off(wave, j * 16 + lan15, mf * 16 + lanhi * 4)) = acc[mf][j];
    __syncthreads();
    waitv0();                                            // gx r,z,h now in regs
    float zg[8];
    {
      float grf[8], gzf[8];
      unpack8<GXBF>(g_r0, g_r1, grf);
      unpack8<GXBF>(g_z0, g_z1, gzf);
      s16x8 rhv;
#pragma unroll
      for (int i = 0; i < 8; ++i) {
        int c = oc + i;
        float rp = grf[i];
        float zp = gzf[i];
#pragma unroll
        for (int w = 0; w < 4; ++w) {
          rp += red[red_off(w, c, ob)];
          zp += red[red_off(w, 32 + c, ob)];
        }
        float r = 1.f / (1.f + __expf(-rp));
        zg[i] = 1.f / (1.f + __expf(-zp));
        rhv[i] = f2bf(r * hown[i]);
      }
      st16(rhb + ob * 512 + c0 + oc, __builtin_bit_cast(u32x4, rhv));   // publish r*h
    }
    tgt += 16; gbarA(bar, tgt);
    // ---- phase 2: wpre = (r*h) @ Whh for own 32 cols ----
    u32x4 rl[4][4];
#pragma unroll
    for (int ks = 0; ks < 4; ++ks)
#pragma unroll
      for (int mf = 0; mf < 4; ++mf)
        rl[ks][mf] = ld16(rhb + (mf * 16 + lan15) * 512 + kw + ks * 32 + ke8);
    waitv0();
    f32x4 acc2[4][2];
#pragma unroll
    for (int i = 0; i < 4; ++i) { acc2[i][0] = z4; acc2[i][1] = z4; }
#pragma unroll
    for (int ks = 0; ks < 4; ++ks) {
#pragma unroll
      for (int mf = 0; mf < 4; ++mf) {
        s16x8 af = __builtin_bit_cast(s16x8, rl[ks][mf]);
        acc2[mf][0] = MFMA16(af, whh[0][ks], acc2[mf][0]);
        acc2[mf][1] = MFMA16(af, whh[1][ks], acc2[mf][1]);
      }
    }
#pragma unroll
    for (int mf = 0; mf < 4; ++mf)
#pragma unroll
      for (int j = 0; j < 2; ++j)
        *(f32x4*)(red + red_off(wave, j * 16 + lan15, mf * 16 + lanhi * 4)) = acc2[mf][j];
    __syncthreads();
    {
      float ghf[8];
      unpack8<GXBF>(g_h0, g_h1, ghf);
      float hn[8];
#pragma unroll
      for (int i = 0; i < 8; ++i) {
        float wp = 0.f;
#pragma unroll
        for (int w = 0; w < 4; ++w) wp += red[red_off(w, oc + i, ob)];
        float pre = ghf[i] + wp;
        pre = fminf(15.f, fmaxf(-15.f, pre));     // guard exp overflow -> NaN
        float e = __expf(-2.f * pre);
        float ht = (1.f - e) / (1.f + e);         // tanh
        hn[i] = (1.f - zg[i]) * hown[i] + zg[i] * ht;
        hown[i] = hn[i];
      }
      u16* hnxt = hb + (cur ^ 1) * (64 * 512);
      s16x8 hv;
#pragma unroll
      for (int i = 0; i < 8; ++i) hv[i] = f2bf(hn[i]);
      st16(hnxt + ob * 512 + c0 + oc, __builtin_bit_cast(u32x4, hv));
      if (layer == 0) {
        *(s16x8*)(out_bf + ((size_t)ob * 512 + t) * 512 + c0 + oc) = hv;
      } else {
        float* o = out_f32 + ((size_t)ob * 512 + t) * 512 + c0 + oc;
#pragma unroll
        for (int i = 0; i < 8; ++i) o[i] = hn[i];
      }
      if (t == 511) {
        float* f = finals + (size_t)(ob * 2 + layer) * 512 + c0 + oc;
#pragma unroll
        for (int i = 0; i < 8; ++i) f[i] = hn[i];
      }
    }
    cur ^= 1;
    tgt += 16;
    if (t != 511) gbarA(bar, tgt);
  }
}

template <int GXBF>
static void run_all(const float* x, const float* h, const float* Wr, const float* br,
                    const float* Wz, const float* bz, const float* Wh, const float* bh,
                    float* out, char* ws, hipStream_t stream) {
  int* sync   = (int*)(ws + OFF_SYNC);
  int* bar0   = sync + 0;    // own 128B line
  int* bar1   = sync + 32;   // own 128B line
  int* claim0 = sync + 64;
  int* claim1 = sync + 72;
  int* winner = sync + 80;   // [80],[81]
  u16* hbAll = (u16*)(ws + OFF_HB);
  u16* rhb   = (u16*)(ws + OFF_RHB);
  u16* WT    = (u16*)(ws + OFF_WT);
  u16* ys0   = (u16*)(ws + OFF_YS0);
  void* gx   = (void*)(ws + OFF_GX);
  float* finals = out + 16777216;

  init_kernel<<<64, 256, 0, stream>>>(h, hbAll, sync);
  convert_w_kernel<<<12288, 256, 0, stream>>>(Wr, Wz, Wh, WT);

  // layer 0 (A = x, f32)
  proj_kernel<1, GXBF><<<3072, 256, 0, stream>>>(x, WT, br, bz, bh, gx);
  recur_kernel<GXBF><<<256, 256, 0, stream>>>(gx, WT, h, hbAll, rhb, ys0, nullptr, finals, 0,
                                              bar0, claim0, winner + 0);
  // layer 1 (A = ys0, bf16)
  proj_kernel<0, GXBF><<<3072, 256, 0, stream>>>(ys0, WT + (size_t)3 * 512 * 1024,
                                                 br + 512, bz + 512, bh + 512, gx);
  recur_kernel<GXBF><<<256, 256, 0, stream>>>(gx, WT + (size_t)3 * 512 * 1024, h, hbAll + 65536, rhb,
                                              nullptr, out, finals, 1,
                                              bar1, claim1, winner + 1);
}

extern "C" void kernel_launch(void* const* d_in, const int* in_sizes, int n_in,
                              void* d_out, int out_size, void* d_ws, size_t ws_size,
                              hipStream_t stream) {
  const float* x  = (const float*)d_in[0];
  const float* h  = (const float*)d_in[1];
  const float* Wr = (const float*)d_in[2];
  const float* br = (const float*)d_in[3];
  const float* Wz = (const float*)d_in[4];
  const float* bz = (const float*)d_in[5];
  const float* Wh = (const float*)d_in[6];
  const float* bh = (const float*)d_in[7];
  float* out = (float*)d_out;
  char* ws = (char*)d_ws;

  const size_t need_f32 = OFF_GX + GX_ELEMS * 4;   // 241,501,184 B (230.3 MiB)
  const size_t need_bf  = OFF_GX + GX_ELEMS * 2;   // 140,837,888 B (134.3 MiB)

  if (ws_size >= need_f32) {
    run_all<0>(x, h, Wr, br, Wz, bz, Wh, bh, out, ws, stream);
  } else if (ws_size >= need_bf) {
    run_all<1>(x, h, Wr, br, Wz, bz, Wh, bh, out, ws, stream);
  } else {
    sentinel_kernel<<<1, 64, 0, stream>>>(out, (float)ws_size);
  }
}

// Round 7
// 7913.014 us; speedup vs baseline: 1.4429x; 1.1194x over previous
//
#include <hip/hip_runtime.h>

typedef unsigned int uint;
typedef unsigned short u16;
typedef short s16x8 __attribute__((ext_vector_type(8)));
typedef float f32x4 __attribute__((ext_vector_type(4)));
typedef uint u32x4 __attribute__((ext_vector_type(4)));
typedef uint u32x2 __attribute__((ext_vector_type(2)));

#define MFMA16(a, b, c) __builtin_amdgcn_mfma_f32_16x16x32_bf16((a), (b), (c), 0, 0, 0)

// ---- problem constants ----
// B=64, S=512, D=512, H=512, L=2
// ws layout (bytes).  sync region = 1024 B:
//   int[0]        bar layer0   (own 128B line, L2-scope atomics only)
//   int[32]       bar layer1   (own 128B line)
//   int[64..71]   claim layer0 (L3-scope line)
//   int[72..79]   claim layer1
//   int[80],[81]  winner layer0/1
static const size_t OFF_SYNC = 0;                      // 1024 B
static const size_t OFF_HB  = 1024;                    // [2 layers][2 bufs][64][512] bf16 = 262144
static const size_t OFF_RHB = 263168;                  // [64][512] bf16 = 65536
static const size_t OFF_WT  = 328704;                  // [2][3][512][1024] bf16 = 6291456
static const size_t OFF_YS0 = 6620160;                 // [64][512][512] bf16 = 33554432
static const size_t OFF_GX  = 40174592;                // [512][64][1536] f32 or bf16
static const size_t GX_ELEMS = (size_t)512 * 64 * 1536;

__device__ __forceinline__ short f2bf(float x) {       // RNE float->bf16
  uint u = __builtin_bit_cast(uint, x);
  u = u + 0x7fffu + ((u >> 16) & 1u);
  return (short)(u >> 16);
}
__device__ __forceinline__ float bf2f(u16 v) {
  uint u = ((uint)v) << 16;
  return __builtin_bit_cast(float, u);
}

// ---- raw memory ops (plain scope: L1 + XCD-L2; co-located workers share the L2) ----
__device__ __forceinline__ u32x4 ld16(const void* p) {
  u32x4 r;
  asm volatile("global_load_dwordx4 %0, %1, off" : "=v"(r) : "v"(p));
  return r;
}
__device__ __forceinline__ u32x2 ld8(const void* p) {
  u32x2 r;
  asm volatile("global_load_dwordx2 %0, %1, off" : "=v"(r) : "v"(p));
  return r;
}
__device__ __forceinline__ void st16(void* p, u32x4 v) {
  asm volatile("global_store_dwordx4 %0, %1, off" :: "v"(p), "v"(v));
}
__device__ __forceinline__ void st8(void* p, u32x2 v) {
  asm volatile("global_store_dwordx2 %0, %1, off" :: "v"(p), "v"(v));
}
__device__ __forceinline__ void waitv0() {
  asm volatile("s_waitcnt vmcnt(0)" ::: "memory");
  __builtin_amdgcn_sched_barrier(0);   // rule #18
}

// ---------------- sentinel ----------------
__global__ void sentinel_kernel(float* __restrict__ out, float v) {
  out[threadIdx.x] = v;
}

// ---------------- init: sync words, h0 -> bf16 ----------------
__global__ void init_kernel(const float* __restrict__ h_in, u16* __restrict__ hb,
                            int* __restrict__ sync) {
  int idx = blockIdx.x * 256 + threadIdx.x;
  if (idx < 256) sync[idx] = (idx == 80 || idx == 81) ? -1 : 0;   // winners = -1
  for (int i = idx; i < 2 * 64 * 512; i += gridDim.x * 256) {
    int l = i >> 15, b = (i >> 9) & 63, c = i & 511;
    hb[l * 65536 + b * 512 + c] = (u16)f2bf(h_in[(b * 2 + l) * 512 + c]);
  }
}

// ---------------- W (L,1024,512) f32 -> WT[l][g][n][k] bf16 (k-major) ----------------
__global__ void convert_w_kernel(const float* __restrict__ Wr, const float* __restrict__ Wz,
                                 const float* __restrict__ Wh, u16* __restrict__ WT) {
  int idx = blockIdx.x * 256 + threadIdx.x;       // 6*512*1024 = 3145728 total
  int n = idx & 511, k = (idx >> 9) & 1023, lg = idx >> 19;
  int l = (lg >= 3) ? 1 : 0, g = lg - l * 3;
  const float* W = (g == 0 ? Wr : (g == 1 ? Wz : Wh)) + (size_t)l * 1024 * 512;
  WT[((size_t)lg * 512 + n) * 1024 + k] = (u16)f2bf(W[k * 512 + n]);
}

// ---------------- input projection GEMM: gx[s][b][g*512+n] = A @ WT_g + bias ----------------
template <int AF32, int GXBF>
__global__ __launch_bounds__(256) void proj_kernel(
    const void* __restrict__ Araw, const u16* __restrict__ WT,
    const float* __restrict__ br, const float* __restrict__ bz, const float* __restrict__ bh,
    void* __restrict__ gx) {
  __shared__ u16 Alds[128 * 64];
  __shared__ u16 Blds[128 * 64];
  const int tid = threadIdx.x;
  const int wave = tid >> 6, lane = tid & 63;
  const int lan15 = lane & 15, lanhi = lane >> 4;
  const int mb = blockIdx.x & 255, nb = blockIdx.x >> 8;
  const int m0 = mb * 128, n0 = nb * 128;
  const int wm = (wave >> 1) * 64, wn = (wave & 1) * 64;

  const f32x4 z4 = {0.f, 0.f, 0.f, 0.f};
  f32x4 acc[4][4];
#pragma unroll
  for (int i = 0; i < 4; ++i)
#pragma unroll
    for (int j = 0; j < 4; ++j) acc[i][j] = z4;

  for (int kb = 0; kb < 512; kb += 64) {
    __syncthreads();
    if constexpr (AF32) {
      const float* A = (const float*)Araw;
#pragma unroll
      for (int p = 0; p < 4; ++p) {        // stage+convert A tile 128x64 (XOR-swizzled 16B slots)
        int idx = p * 256 + tid;
        int row = idx >> 3, slot = idx & 7;
        const float* src = A + (size_t)(m0 + row) * 512 + kb + slot * 8;
        float4 v0 = *(const float4*)src;
        float4 v1 = *(const float4*)(src + 4);
        u16 tmp[8] = {(u16)f2bf(v0.x), (u16)f2bf(v0.y), (u16)f2bf(v0.z), (u16)f2bf(v0.w),
                      (u16)f2bf(v1.x), (u16)f2bf(v1.y), (u16)f2bf(v1.z), (u16)f2bf(v1.w)};
        *(uint4*)((char*)Alds + row * 128 + ((slot ^ (row & 7)) * 16)) = *(uint4*)tmp;
      }
    } else {
      const u16* A = (const u16*)Araw;
#pragma unroll
      for (int p = 0; p < 4; ++p) {
        int idx = p * 256 + tid;
        int row = idx >> 3, slot = idx & 7;
        uint4 v = *(const uint4*)(A + (size_t)(m0 + row) * 512 + kb + slot * 8);
        *(uint4*)((char*)Alds + row * 128 + ((slot ^ (row & 7)) * 16)) = v;
      }
    }
#pragma unroll
    for (int p = 0; p < 4; ++p) {          // stage B tile 128x64 from WT (n-major rows)
      int idx = p * 256 + tid;
      int row = idx >> 3, slot = idx & 7;
      int ng = n0 + row, g = ng >> 9, nc = ng & 511;
      uint4 v = *(const uint4*)(WT + ((size_t)g * 512 + nc) * 1024 + kb + slot * 8);
      *(uint4*)((char*)Blds + row * 128 + ((slot ^ (row & 7)) * 16)) = v;
    }
    __syncthreads();
#pragma unroll
    for (int ks = 0; ks < 2; ++ks) {
      s16x8 af[4], bfr[4];
#pragma unroll
      for (int f = 0; f < 4; ++f) {
        int rowA = wm + f * 16 + lan15;
        af[f] = *(const s16x8*)((const char*)Alds + rowA * 128 + (((ks * 4 + lanhi) ^ (rowA & 7)) * 16));
        int rowB = wn + f * 16 + lan15;
        bfr[f] = *(const s16x8*)((const char*)Blds + rowB * 128 + (((ks * 4 + lanhi) ^ (rowB & 7)) * 16));
      }
#pragma unroll
      for (int mf = 0; mf < 4; ++mf)
#pragma unroll
        for (int nf = 0; nf < 4; ++nf)
          acc[mf][nf] = MFMA16(af[mf], bfr[nf], acc[mf][nf]);
    }
  }
#pragma unroll
  for (int nf = 0; nf < 4; ++nf) {
    int n = n0 + wn + nf * 16 + lan15;
    int g = n >> 9, nc = n & 511;
    float bias = (g == 0 ? br[nc] : (g == 1 ? bz[nc] : bh[nc]));
#pragma unroll
    for (int mf = 0; mf < 4; ++mf) {
#pragma unroll
      for (int q = 0; q < 4; ++q) {
        int m = m0 + wm + mf * 16 + lanhi * 4 + q;
        int s = m & 511, b = m >> 9;
        size_t e = (size_t)(s * 64 + b) * 1536 + n;
        float v = acc[mf][nf][q] + bias;
        if constexpr (GXBF) ((u16*)gx)[e] = (u16)f2bf(v);
        else ((float*)gx)[e] = v;
      }
    }
  }
}

// ---------------- XCD-local barrier: L2-executed atomics (R6-proven) ----------------
__device__ __forceinline__ void gbarA(int* bar, int target) {
  asm volatile("s_waitcnt vmcnt(0)" ::: "memory");   // my exchange stores are in L2
  __syncthreads();                                   // whole WG's stores are in L2
  if (threadIdx.x == 0) {
    int one = 1;
    asm volatile("global_atomic_add %0, %1, off" :: "v"(bar), "v"(one) : "memory");
    int v, zero = 0, iter = 0;
    do {
      __builtin_amdgcn_s_sleep(1);
      asm volatile("global_atomic_add %0, %1, %2, off sc0\n\ts_waitcnt vmcnt(0)"
                   : "=v"(v) : "v"(bar), "v"(zero) : "memory");
    } while (v < target && ++iter < (1 << 17));      // watchdog: fail wrong, not hung
  }
  __syncthreads();
  __builtin_amdgcn_sched_barrier(0);
}

// red buffer: [4 waves][32 cols][64 batches] f32, 16B-slot XOR swizzle on batch
__device__ __forceinline__ int red_off32(int w, int c, int b) {
  return ((w * 32 + c) << 6) + ((((b >> 2) ^ (c & 15)) & 15) << 2) + (b & 3);
}

template <int GXBF>
__device__ __forceinline__ void unpack4(const u32x4& a4, const u32x2& a2, float o[4]) {
  if constexpr (GXBF) {
    const u16* p = (const u16*)&a2;
#pragma unroll
    for (int i = 0; i < 4; ++i) o[i] = bf2f(p[i]);
  } else {
    const float* p = (const float*)&a4;
#pragma unroll
    for (int i = 0; i < 4; ++i) o[i] = p[i];
  }
}

// ---------------- persistent recurrent kernel ----------------
// grid=256, 84KB LDS -> exactly 1 WG/CU -> every XCD hosts exactly 32 WGs.
// Election: first 32 claimants of the winning XCD become workers (one full XCD).
template <int GXBF>
__global__ __launch_bounds__(256, 1) void recur_kernel(
    const void* __restrict__ gx,     // [512][64][1536] f32 or bf16
    const u16* __restrict__ WT,      // layer base [3][512][1024], recurrent part k in [512,1024)
    const float* __restrict__ h_in,  // [64][2][512]
    u16* __restrict__ hb,            // [2][64][512] bf16 double buffer (this layer)
    u16* __restrict__ rhb,           // [64][512] bf16
    u16* __restrict__ out_bf,        // layer0: ys0 [b][t][c]
    float* __restrict__ out_f32,     // layer1: d_out [b][t][c]
    float* __restrict__ finals,      // d_out + B*S*H, [b][l][c]
    const int layer, int* __restrict__ bar,
    int* __restrict__ claim, int* __restrict__ winner) {
  __shared__ float red[21504];       // 84 KiB: forces 1 WG/CU (2x84KB > 160KB)
  __shared__ int s_slot;

  if (threadIdx.x == 0) {
    int xcc;
    asm volatile("s_getreg_b32 %0, hwreg(HW_REG_XCC_ID)" : "=s"(xcc));
    xcc &= 7;
    int slot = __hip_atomic_fetch_add(&claim[xcc], 1, __ATOMIC_RELAXED, __HIP_MEMORY_SCOPE_AGENT);
    int my = -1;
    if (slot < 32) {
      if (slot == 31) {
        int expected = -1;
        __hip_atomic_compare_exchange_strong(winner, &expected, xcc, __ATOMIC_RELAXED,
                                             __ATOMIC_RELAXED, __HIP_MEMORY_SCOPE_AGENT);
      }
      int w, it = 0;
      do {
        __builtin_amdgcn_s_sleep(8);
        w = __hip_atomic_load(winner, __ATOMIC_RELAXED, __HIP_MEMORY_SCOPE_AGENT);
      } while (w < 0 && ++it < (1 << 22));   // watchdog
      my = (w == xcc) ? slot : -1;
    }
    s_slot = my;
  }
  __syncthreads();
  const int slot = s_slot;
  if (slot < 0) return;

  const int tid = threadIdx.x;
  const int wave = tid >> 6, lane = tid & 63;
  const int lan15 = lane & 15, lanhi = lane >> 4;
  const int c0 = slot * 16;           // owned h-columns [c0, c0+16)
  const int kw = wave * 128;          // K-split per wave
  const int ke8 = lanhi * 8;
  const int ES = GXBF ? 2 : 4;

  // recurrent-weight fragments -> registers (one-time): 16 cols per gate
  s16x8 wrz[2][4];   // [gate r/z][kstep]
  s16x8 whh[4];
#pragma unroll
  for (int g = 0; g < 2; ++g)
#pragma unroll
    for (int ks = 0; ks < 4; ++ks)
      wrz[g][ks] = *(const s16x8*)(WT + ((size_t)(g * 512 + c0 + lan15)) * 1024 + 512 + kw + ks * 32 + ke8);
#pragma unroll
  for (int ks = 0; ks < 4; ++ks)
    whh[ks] = *(const s16x8*)(WT + ((size_t)(1024 + c0 + lan15)) * 1024 + 512 + kw + ks * 32 + ke8);

  // fp32 h state: thread owns batch ob, 4 cols at c0+oc
  const int ob = tid >> 2, oc = (tid & 3) * 4;
  float hown[4];
#pragma unroll
  for (int i = 0; i < 4; ++i) hown[i] = h_in[(ob * 2 + layer) * 512 + c0 + oc + i];

  // gx prefetch registers (r,z single-buffered; h double-buffered)
  u32x4 pf_r4 = {0,0,0,0}, pf_z4 = {0,0,0,0}, pf_hc4 = {0,0,0,0}, pf_hn4 = {0,0,0,0};
  u32x2 pf_r2 = {0,0}, pf_z2 = {0,0}, pf_hc2 = {0,0}, pf_hn2 = {0,0};
  auto issue_pf = [&](int tp) {
    const char* gq = (const char*)gx + ((size_t)(tp * 64 + ob) * 1536 + c0 + oc) * ES;
    if constexpr (GXBF) {
      pf_r2 = ld8(gq);
      pf_z2 = ld8(gq + 512 * 2);
      pf_hn2 = ld8(gq + 1024 * 2);
    } else {
      pf_r4 = ld16(gq);
      pf_z4 = ld16(gq + 512 * 4);
      pf_hn4 = ld16(gq + 1024 * 4);
    }
  };
  issue_pf(0);   // prologue: gx(0) in flight

  const f32x4 z4 = {0.f, 0.f, 0.f, 0.f};
  int cur = 0, tgt = 0;

  for (int t = 0; t < 512; ++t) {
    const u16* hcur = hb + cur * (64 * 512);
    // ---- phase 1: [r|z]pre = h @ [Wrh|Wzh] for own 2x16 gate-cols, K-split 4 waves ----
    u32x4 hl[4][4];
#pragma unroll
    for (int ks = 0; ks < 4; ++ks)
#pragma unroll
      for (int mf = 0; mf < 4; ++mf)
        hl[ks][mf] = ld16(hcur + (mf * 16 + lan15) * 512 + kw + ks * 32 + ke8);
    waitv0();                                  // hl + pf(t) retired
    f32x4 acc[4][2];
#pragma unroll
    for (int i = 0; i < 4; ++i) { acc[i][0] = z4; acc[i][1] = z4; }
#pragma unroll
    for (int ks = 0; ks < 4; ++ks) {
#pragma unroll
      for (int mf = 0; mf < 4; ++mf) {
        s16x8 af = __builtin_bit_cast(s16x8, hl[ks][mf]);
        acc[mf][0] = MFMA16(af, wrz[0][ks], acc[mf][0]);
        acc[mf][1] = MFMA16(af, wrz[1][ks], acc[mf][1]);
      }
    }
#pragma unroll
    for (int mf = 0; mf < 4; ++mf)
#pragma unroll
      for (int g = 0; g < 2; ++g)
        *(f32x4*)(red + red_off32(wave, g * 16 + lan15, mf * 16 + lanhi * 4)) = acc[mf][g];
    __syncthreads();
    float zg[4];
    {
      float grf[4], gzf[4];
      unpack4<GXBF>(pf_r4, pf_r2, grf);
      unpack4<GXBF>(pf_z4, pf_z2, gzf);
      u16 rh[4];
#pragma unroll
      for (int i = 0; i < 4; ++i) {
        float rp = grf[i], zp = gzf[i];
#pragma unroll
        for (int w = 0; w < 4; ++w) {
          rp += red[red_off32(w, oc + i, ob)];
          zp += red[red_off32(w, 16 + oc + i, ob)];
        }
        float r = 1.f / (1.f + __expf(-rp));
        zg[i] = 1.f / (1.f + __expf(-zp));
        rh[i] = (u16)f2bf(r * hown[i]);
      }
      st8(rhb + ob * 512 + c0 + oc, __builtin_bit_cast(u32x2, rh));   // publish r*h
    }
    tgt += 32; gbarA(bar, tgt);
    // ---- phase 2: wpre = (r*h) @ Whh for own 16 cols ----
    pf_hc4 = pf_hn4; pf_hc2 = pf_hn2;          // gx_h(t) now current
    u32x4 rl[4][4];
#pragma unroll
    for (int ks = 0; ks < 4; ++ks)
#pragma unroll
      for (int mf = 0; mf < 4; ++mf)
        rl[ks][mf] = ld16(rhb + (mf * 16 + lan15) * 512 + kw + ks * 32 + ke8);
    issue_pf(t < 511 ? t + 1 : 511);           // prefetch gx(t+1), stays in flight
    asm volatile("s_waitcnt vmcnt(3)" ::: "memory");   // rl done, pf outstanding
    __builtin_amdgcn_sched_barrier(0);
    f32x4 acc2[4];
#pragma unroll
    for (int i = 0; i < 4; ++i) acc2[i] = z4;
#pragma unroll
    for (int ks = 0; ks < 4; ++ks)
#pragma unroll
      for (int mf = 0; mf < 4; ++mf)
        acc2[mf] = MFMA16(__builtin_bit_cast(s16x8, rl[ks][mf]), whh[ks], acc2[mf]);
#pragma unroll
    for (int mf = 0; mf < 4; ++mf)
      *(f32x4*)(red + red_off32(wave, lan15, mf * 16 + lanhi * 4)) = acc2[mf];
    __syncthreads();
    float hn[4];
    u16 hv[4];
    {
      float ghf[4];
      unpack4<GXBF>(pf_hc4, pf_hc2, ghf);
#pragma unroll
      for (int i = 0; i < 4; ++i) {
        float wp = 0.f;
#pragma unroll
        for (int w = 0; w < 4; ++w) wp += red[red_off32(w, oc + i, ob)];
        float pre = ghf[i] + wp;
        pre = fminf(15.f, fmaxf(-15.f, pre));     // guard exp overflow -> NaN
        float e = __expf(-2.f * pre);
        float ht = (1.f - e) / (1.f + e);         // tanh
        hn[i] = (1.f - zg[i]) * hown[i] + zg[i] * ht;
        hown[i] = hn[i];
        hv[i] = (u16)f2bf(hn[i]);
      }
      st8(hb + (cur ^ 1) * (64 * 512) + ob * 512 + c0 + oc, __builtin_bit_cast(u32x2, hv));
    }
    cur ^= 1;
    tgt += 32;
    if (t != 511) gbarA(bar, tgt);
    // outputs post-barrier: peers never wait on these acks
    if (layer == 0) {
      st8(out_bf + ((size_t)ob * 512 + t) * 512 + c0 + oc, __builtin_bit_cast(u32x2, hv));
    } else {
      f32x4 o = {hn[0], hn[1], hn[2], hn[3]};
      st16(out_f32 + ((size_t)ob * 512 + t) * 512 + c0 + oc, __builtin_bit_cast(u32x4, o));
    }
    if (t == 511) {
      float* f = finals + (size_t)(ob * 2 + layer) * 512 + c0 + oc;
#pragma unroll
      for (int i = 0; i < 4; ++i) f[i] = hn[i];
    }
  }
}

template <int GXBF>
static void run_all(const float* x, const float* h, const float* Wr, const float* br,
                    const float* Wz, const float* bz, const float* Wh, const float* bh,
                    float* out, char* ws, hipStream_t stream) {
  int* sync   = (int*)(ws + OFF_SYNC);
  int* bar0   = sync + 0;    // own 128B line
  int* bar1   = sync + 32;   // own 128B line
  int* claim0 = sync + 64;
  int* claim1 = sync + 72;
  int* winner = sync + 80;   // [80],[81]
  u16* hbAll = (u16*)(ws + OFF_HB);
  u16* rhb   = (u16*)(ws + OFF_RHB);
  u16* WT    = (u16*)(ws + OFF_WT);
  u16* ys0   = (u16*)(ws + OFF_YS0);
  void* gx   = (void*)(ws + OFF_GX);
  float* finals = out + 16777216;

  init_kernel<<<64, 256, 0, stream>>>(h, hbAll, sync);
  convert_w_kernel<<<12288, 256, 0, stream>>>(Wr, Wz, Wh, WT);

  // layer 0 (A = x, f32)
  proj_kernel<1, GXBF><<<3072, 256, 0, stream>>>(x, WT, br, bz, bh, gx);
  recur_kernel<GXBF><<<256, 256, 0, stream>>>(gx, WT, h, hbAll, rhb, ys0, nullptr, finals, 0,
                                              bar0, claim0, winner + 0);
  // layer 1 (A = ys0, bf16)
  proj_kernel<0, GXBF><<<3072, 256, 0, stream>>>(ys0, WT + (size_t)3 * 512 * 1024,
                                                 br + 512, bz + 512, bh + 512, gx);
  recur_kernel<GXBF><<<256, 256, 0, stream>>>(gx, WT + (size_t)3 * 512 * 1024, h, hbAll + 65536, rhb,
                                              nullptr, out, finals, 1,
                                              bar1, claim1, winner + 1);
}

extern "C" void kernel_launch(void* const* d_in, const int* in_sizes, int n_in,
                              void* d_out, int out_size, void* d_ws, size_t ws_size,
                              hipStream_t stream) {
  const float* x  = (const float*)d_in[0];
  const float* h  = (const float*)d_in[1];
  const float* Wr = (const float*)d_in[2];
  const float* br = (const float*)d_in[3];
  const float* Wz = (const float*)d_in[4];
  const float* bz = (const float*)d_in[5];
  const float* Wh = (const float*)d_in[6];
  const float* bh = (const float*)d_in[7];
  float* out = (float*)d_out;
  char* ws = (char*)d_ws;

  const size_t need_f32 = OFF_GX + GX_ELEMS * 4;   // 241,501,184 B (230.3 MiB)
  const size_t need_bf  = OFF_GX + GX_ELEMS * 2;   // 140,837,888 B (134.3 MiB)

  if (ws_size >= need_f32) {
    run_all<0>(x, h, Wr, br, Wz, bz, Wh, bh, out, ws, stream);
  } else if (ws_size >= need_bf) {
    run_all<1>(x, h, Wr, br, Wz, bz, Wh, bh, out, ws, stream);
  } else {
    sentinel_kernel<<<1, 64, 0, stream>>>(out, (float)ws_size);
  }
}